// Round 6
// baseline (111.539 us; speedup 1.0000x reference)
//
#include <hip/hip_runtime.h>
#include <stdint.h>

#define BB 4
#define NN 2048
#define CC 3
#define MM (NN * (CC - 1)) /* 4096 */
#define MAXDET 100
#define SCORE_THR 0.05f
#define NMS_THR 0.5f
#define MIN_SIZE 0.01f
#define TTARGET 256 /* selection prefix size (scan depth ~115 on this data) */
#define SSKCAP 1024 /* fast-path sort buffer capacity */
#define TILE 128    /* NMS tile size */

// out layout: boxes[4,100,4] ++ scores[4,100] ++ labels[4,100] ++ keep[4,100]
#define SCORE_OFF (BB * MAXDET * 4)         /* 1600 */
#define LABEL_OFF (SCORE_OFF + BB * MAXDET) /* 2000 */
#define KEEP_OFF (LABEL_OFF + BB * MAXDET)  /* 2400 */
// per-image scratch stash (scores rows 96..99): decode writes, nms reads,
// then nms's output phase overwrites. Block-private, no races.
#define STASH(b, j) (SCORE_OFF + (b) * MAXDET + 96 + (j))

// Wave-local LDS sync (r4-validated): drains this wave's LDS ops + pins
// compiler scheduling. Sufficient when all exchanging threads are one wave.
__device__ __forceinline__ void wave_lds_sync() {
  __builtin_amdgcn_wave_barrier();
  __builtin_amdgcn_s_waitcnt(0xC07F); // vmcnt(63) expcnt(7) lgkmcnt(0)
  __builtin_amdgcn_wave_barrier();
}

// Exact reference IoU>thr test (validated absmax=0 across rounds 1-5).
__device__ __forceinline__ bool iou_gt(const float4 A, const float aA,
                                       const float4 B, const float aB) {
#pragma clang fp contract(off)
  float ltx = fmaxf(A.x, B.x), lty = fmaxf(A.y, B.y);
  float rbx = fminf(A.z, B.z), rby = fminf(A.w, B.w);
  float iw = fmaxf(rbx - ltx, 0.0f), ih = fmaxf(rby - lty, 0.0f);
  float inter = iw * ih;
  float denom = ((aA + aB) - inter) + 1e-7f;
  return inter / denom > NMS_THR;
}

// ---------------------------------------------------------------------------
// decode: one thread per proposal (8192 threads, 16 blocks). Writes candidate
// boxes + keys (key=0 for invalid), global score-bin histogram (1024 bins per
// image, pre-zeroed via hipMemsetAsync), and per-block coord max to the stash.
// FP arithmetic bitwise-identical to the validated rounds-1..5 path.
// ---------------------------------------------------------------------------
__global__ __launch_bounds__(512) void decode_kernel(const float* __restrict__ logits,
                                                     const float* __restrict__ rel,
                                                     const float* __restrict__ props,
                                                     const int* __restrict__ ph,
                                                     const int* __restrict__ pw,
                                                     float4* __restrict__ cand_box,
                                                     unsigned long long* __restrict__ keys,
                                                     unsigned* __restrict__ hist_g,
                                                     float* __restrict__ out) {
#pragma clang fp contract(off)
  __shared__ float red[512];
  int tid = threadIdx.x;
  int t = blockIdx.x * 512 + tid; // proposal index; block spans one image only
  int b = t >> 11;
  int n = t & 2047;
  float Hf = (float)ph[0];
  float Wf = (float)pw[0];

  const float* lg = logits + (size_t)t * CC;
  float l0 = lg[0], l1 = lg[1], l2 = lg[2];
  float mx = fmaxf(l0, fmaxf(l1, l2));
  float e0 = expf(l0 - mx), e1 = expf(l1 - mx), e2 = expf(l2 - mx);
  float ssum = (e0 + e1) + e2;

  float4 pr = ((const float4*)props)[t];
  float w = pr.z - pr.x, h = pr.w - pr.y;
  float cx = pr.x + 0.5f * w, cy = pr.y + 0.5f * h;
  const float4* rl = (const float4*)(rel + (size_t)t * 12);
  const float SCALE_CLAMP = 4.135166556742356f; // log(1000/16) as f32

  float lmax = 0.0f;
  for (int c = 1; c < CC; ++c) {
    float4 rv = rl[c];
    float score = (c == 1 ? e1 : e2) / ssum;
    float dx = rv.x / 10.0f;
    float dy = rv.y / 10.0f;
    float dw = fminf(rv.z / 5.0f, SCALE_CLAMP);
    float dh = fminf(rv.w / 5.0f, SCALE_CLAMP);
    float pcx = dx * w + cx;
    float pcy = dy * h + cy;
    float bw = expf(dw) * w;
    float bh = expf(dh) * h;
    float x1 = pcx - 0.5f * bw, y1 = pcy - 0.5f * bh;
    float x2 = pcx + 0.5f * bw, y2 = pcy + 0.5f * bh;
    x1 = fminf(fmaxf(x1, 0.0f), Wf);
    y1 = fminf(fmaxf(y1, 0.0f), Hf);
    x2 = fminf(fmaxf(x2, 0.0f), Wf);
    y2 = fminf(fmaxf(y2, 0.0f), Hf);

    // jnp.max(boxes) is over ALL candidate boxes (incl. invalid)
    lmax = fmaxf(lmax, fmaxf(fmaxf(x1, y1), fmaxf(x2, y2)));

    bool valid = (score > SCORE_THR) && (x2 - x1 >= MIN_SIZE) && (y2 - y1 >= MIN_SIZE);
    int m = n * (CC - 1) + (c - 1);
    cand_box[(size_t)b * MM + m] = make_float4(x1, y1, x2, y2);
    unsigned long long key = 0ull;
    if (valid) {
      unsigned sb = __float_as_uint(score);
      key = (((unsigned long long)sb) << 32) |
            (unsigned long long)(0xFFFFFFFFu - (unsigned)m);
      // bin = score bits[25:16]; monotone in score over (0.05,1] (bits[31:26]
      // constant). Validated rounds 3-5.
      atomicAdd(&hist_g[b * 1024 + ((sb >> 16) & 1023)], 1u);
    }
    keys[(size_t)b * MM + m] = key;
  }

  red[tid] = lmax;
  __syncthreads();
  for (int s2 = 256; s2 > 0; s2 >>= 1) {
    if (tid < s2) red[tid] = fmaxf(red[tid], red[tid + s2]);
    __syncthreads();
  }
  if (tid == 0) out[STASH(b, blockIdx.x & 3)] = red[0];
}

// ---------------------------------------------------------------------------
// Single-wave bitonic sort (descending, zeros sink). Caller: only wave 0
// executes; all exchanges are within one wave -> no __syncthreads needed,
// only wave-local LDS drains between stages. Caller barriers before/after.
// ---------------------------------------------------------------------------
__device__ void bitonic_sort_desc_wave0(unsigned long long* a, int P, int lane) {
  for (int size = 2; size <= P; size <<= 1) {
    for (int stride = size >> 1; stride > 0; stride >>= 1) {
      wave_lds_sync();
      for (int i = lane; i < (P >> 1); i += 64) {
        int lo = 2 * i - (i & (stride - 1));
        int hi = lo + stride;
        bool asc = ((lo & size) != 0);
        unsigned long long x = a[lo], y = a[hi];
        if ((x > y) == asc) { a[lo] = y; a[hi] = x; }
      }
    }
  }
  wave_lds_sync();
}

// ---------------------------------------------------------------------------
// Block-wide hybrid bitonic sort (fallback path only; r4-validated).
// ---------------------------------------------------------------------------
__device__ void bitonic_sort_desc(unsigned long long* a, int P, int tid) {
  int prev_big = 1;
  for (int size = 2; size <= P; size <<= 1) {
    for (int stride = size >> 1; stride > 0; stride >>= 1) {
      int big = (stride >= 128);
      if (big | prev_big) __syncthreads(); else wave_lds_sync();
      for (int i = tid; i < (P >> 1); i += 512) {
        int lo = 2 * i - (i & (stride - 1));
        int hi = lo + stride;
        bool asc = ((lo & size) != 0);
        unsigned long long x = a[lo], y = a[hi];
        if ((x > y) == asc) { a[lo] = y; a[hi] = x; }
      }
      prev_big = big;
    }
  }
  __syncthreads();
}

// ---------------------------------------------------------------------------
// Mask-based tiled greedy NMS over a sorted key array (r5-validated, exact).
// use_map: boxes come from LDS (sboxall[map[m]]) instead of global cbg[m].
// Whole block must call (contains barriers). Returns final kept count.
// ---------------------------------------------------------------------------
__device__ int tiled_nms(const unsigned long long* keys_s, int count,
                         const float4* __restrict__ cbg, float off_base,
                         const float4* sboxall, const unsigned short* map, int use_map,
                         float4* tob, float4* trb, float* tarea,
                         ulonglong2* smask, int* sflag, int* knew,
                         float4* kept_ob, float4* kept_raw, float* kept_area,
                         unsigned long long* kept_key, int* s_nnew, int tid) {
#pragma clang fp contract(off)
  int wv = tid >> 6, lane = tid & 63;
  int cnt = 0;
  for (int base = 0; base < count && cnt < MAXDET; base += TILE) {
    int tsz = (count - base < TILE) ? (count - base) : TILE;
    // gather tile: raw box, offset box, area (exact offset arithmetic)
    if (tid < tsz) {
      unsigned long long key = keys_s[base + tid];
      int m = (int)(0xFFFFFFFFu - (unsigned)key);
      float4 bx = use_map ? sboxall[map[m]] : cbg[m];
      int lbl = (m & 1) + 1;
      float off = (float)lbl * off_base;
      float4 ob = make_float4(bx.x + off, bx.y + off, bx.z + off, bx.w + off);
      tob[tid] = ob;
      trb[tid] = bx;
      tarea[tid] = (ob.z - ob.x) * (ob.w - ob.y);
    }
    __syncthreads();

    // per-lane register copies (invariant across rows of this tile)
    float4 bi0 = tob[lane];
    float ai0 = tarea[lane];
    float4 bi1 = tob[lane + 64];
    float ai1 = tarea[lane + 64];
    float4 kb0 = kept_ob[(lane < cnt) ? lane : 0];
    float ka0 = kept_area[(lane < cnt) ? lane : 0];
    float4 kb1 = kept_ob[(lane + 64 < cnt) ? lane + 64 : 0];
    float ka1 = kept_area[(lane + 64 < cnt) ? lane + 64 : 0];

    // matrix phase: wave wv handles rows j = wv, wv+8, ...
    for (int j = wv; j < tsz; j += 8) {
      float4 aj = tob[j];
      float aaj = tarea[j];
      unsigned long long w0 = 0ull, w1 = 0ull;
      if (j < 63) {
        bool p = (lane > j) && (lane < tsz) && iou_gt(aj, aaj, bi0, ai0);
        w0 = __ballot(p);
      }
      if (j < 127) {
        int i = lane + 64;
        bool p = (i > j) && (i < tsz) && iou_gt(aj, aaj, bi1, ai1);
        w1 = __ballot(p);
      }
      bool s = false;
      if (cnt > 0) {
        if (lane < cnt && iou_gt(kb0, ka0, aj, aaj)) s = true;
        if (cnt > 64 && lane + 64 < cnt && iou_gt(kb1, ka1, aj, aaj)) s = true;
      }
      int anyk = __any(s);
      if (lane == 0) {
        smask[j].x = w0;
        smask[j].y = w1;
        sflag[j] = anyk;
      }
    }
    __syncthreads();

    // serial bit reduction on wave 0: rows in lane regs, fetched via shfl.
    if (tid < 64) {
      int iA = 2 * lane, iB = 2 * lane + 1;
      ulonglong2 rA = smask[(iA < tsz) ? iA : 0];
      ulonglong2 rB = smask[(iB < tsz) ? iB : 0];
      int fA = sflag[(iA < tsz) ? iA : 0];
      int fB = sflag[(iB < tsz) ? iB : 0];
      unsigned long long r0 = 0ull, r1 = 0ull;
      int c = cnt, nk = 0;
      for (int j = 0; j < tsz; ++j) {
        int src = j >> 1;
        unsigned long long m0 = __shfl((j & 1) ? rB.x : rA.x, src);
        unsigned long long m1 = __shfl((j & 1) ? rB.y : rA.y, src);
        int fl = __shfl((j & 1) ? fB : fA, src);
        bool rem = (j < 64) ? ((r0 >> j) & 1ull) : ((r1 >> (j - 64)) & 1ull);
        if (!rem && !fl) {
          if (lane == 0) knew[nk] = j;
          nk++;
          c++;
          r0 |= m0;
          r1 |= m1;
          if (c >= MAXDET) break;
        }
      }
      if (lane == 0) *s_nnew = nk;
    }
    __syncthreads();

    // append new keeps (parallel)
    int nnew = *s_nnew;
    if (tid < nnew) {
      int j = knew[tid];
      kept_ob[cnt + tid] = tob[j];
      kept_raw[cnt + tid] = trb[j];
      kept_area[cnt + tid] = tarea[j];
      kept_key[cnt + tid] = keys_s[base + j];
    }
    cnt += nnew;
    __syncthreads();
  }
  return cnt;
}

// ---------------------------------------------------------------------------
// nms_kernel: one block per image.
//  wave0 loads precomputed histogram + suffix-scans threshold, other waves
//  load keys -> ballot-compaction with inline coalesced box staging into LDS
//  (map[m]->pos) -> single-wave barrier-free bitonic sort of prefix (P<=1024)
//  -> tiled NMS (LDS-only gathers). Fallbacks: T>SSKCAP or prefix
//  insufficient -> full 4096 block sort + tiled NMS w/ global gathers.
// ---------------------------------------------------------------------------
__global__ __launch_bounds__(512) void nms_kernel(const float4* __restrict__ cand_box,
                                                  const unsigned long long* __restrict__ keys,
                                                  const unsigned* __restrict__ hist_g,
                                                  float* __restrict__ out) {
#pragma clang fp contract(off)
  __shared__ __align__(16) unsigned long long sk[MM];      // 32 KB (fallback)
  __shared__ __align__(16) unsigned long long ssk[SSKCAP]; // 8 KB selected keys
  __shared__ __align__(16) float4 sbox[SSKCAP];            // 16 KB staged boxes
  __shared__ unsigned short map[MM];                       // 8 KB m -> sbox pos
  __shared__ __align__(16) float4 tob[TILE];
  __shared__ __align__(16) float4 trb[TILE];
  __shared__ float tarea[TILE];
  __shared__ __align__(16) ulonglong2 smask[TILE];
  __shared__ int sflag[TILE];
  __shared__ int knew[TILE];
  __shared__ float4 kept_ob[MAXDET];
  __shared__ float4 kept_raw[MAXDET];
  __shared__ float kept_area[MAXDET];
  __shared__ unsigned long long kept_key[MAXDET];
  __shared__ int s_scnt, s_thr, s_vtot, s_cnt, s_fb, s_nnew;

  int b = blockIdx.x;
  int tid = threadIdx.x;
  int lane = tid & 63;
  const float4* cbg = cand_box + (size_t)b * MM;

  // coalesced key loads into registers (all waves, issued first)
  const ulonglong2* kg = (const ulonglong2*)(keys + (size_t)b * MM);
  ulonglong2 kr[4];
#pragma unroll
  for (int j = 0; j < 4; ++j) kr[j] = kg[j * 512 + tid];

  if (tid == 0) { s_scnt = 0; s_fb = 0; s_cnt = 0; }
  // per-image max from decode stash -> offset base (reference: max(boxes)+1)
  float m01 = fmaxf(out[STASH(b, 0)], out[STASH(b, 1)]);
  float m23 = fmaxf(out[STASH(b, 2)], out[STASH(b, 3)]);
  float off_base = fmaxf(m01, m23) + 1.0f;

  // wave 0: load this image's 1024-bin histogram (coalesced 4 KB) and
  // suffix-scan for the threshold bin (largest bin with suffix >= TTARGET).
  if (tid < 64) {
    const unsigned* hg = hist_g + b * 1024 + tid * 16;
    unsigned own[16];
#pragma unroll
    for (int i = 0; i < 16; ++i) own[i] = hg[i];
    unsigned psum = 0;
#pragma unroll
    for (int i = 0; i < 16; ++i) psum += own[i];
    unsigned s = psum;
    for (int d = 1; d < 64; d <<= 1) {
      unsigned o = __shfl_down(s, d);
      if (tid + d < 64) s += o;
    }
    unsigned after = s - psum;
    int best = -1;
    unsigned run = after;
#pragma unroll
    for (int i = 15; i >= 0; --i) {
      run += own[i];
      if (best < 0 && run >= TTARGET) best = tid * 16 + i;
    }
    int gb = best;
    for (int d = 1; d < 64; d <<= 1) {
      int o = __shfl_down(gb, d);
      if (tid + d < 64) gb = (o > gb) ? o : gb;
    }
    if (tid == 0) {
      s_thr = (gb < 0) ? 0 : gb;
      s_vtot = (int)s;
    }
  }
  __syncthreads();
  int thr = s_thr;
  int Vtot = s_vtot;

  // ballot-compaction of selected keys into ssk, with inline coalesced box
  // staging: thread tid owns m0=1024j+2tid and m0+1; box reads are contiguous
  // across the wave. map[m]=pos enables LDS-only tile gathers later.
#pragma unroll
  for (int j = 0; j < 4; ++j) {
    int m0 = 1024 * j + 2 * tid;
    float4 b0 = cbg[m0];
    float4 b1 = cbg[m0 + 1];
#pragma unroll
    for (int half = 0; half < 2; ++half) {
      unsigned long long key = half ? kr[j].y : kr[j].x;
      unsigned hik = (unsigned)(key >> 32);
      bool pred = (hik != 0u) && ((int)((hik >> 16) & 1023) >= thr);
      unsigned long long mask = __ballot(pred);
      int ofs = __popcll(mask & ((1ull << lane) - 1ull));
      int basea = 0;
      if (lane == 0 && mask) basea = atomicAdd(&s_scnt, (int)__popcll(mask));
      basea = __shfl(basea, 0);
      if (pred) {
        int pos = basea + ofs;
        if (pos < SSKCAP) {
          ssk[pos] = key;
          sbox[pos] = half ? b1 : b0;
          map[m0 + half] = (unsigned short)pos;
        }
      }
    }
  }
  __syncthreads();
  int T = s_scnt;

  if (T <= SSKCAP) {
    int P = 1;
    while (P < T) P <<= 1;
    for (int i = T + tid; i < P; i += 512) ssk[i] = 0ull;
    __syncthreads();
    if (tid < 64) bitonic_sort_desc_wave0(ssk, P, lane); // barrier-free
    __syncthreads();
    int cnt = tiled_nms(ssk, T, cbg, off_base, sbox, map, 1, tob, trb, tarea,
                        smask, sflag, knew, kept_ob, kept_raw, kept_area,
                        kept_key, &s_nnew, tid);
    if (tid == 0) {
      s_cnt = cnt;
      s_fb = (cnt < MAXDET && T < Vtot) ? 1 : 0; // prefix insufficient
    }
  } else {
    if (tid == 0) s_fb = 1; // selection overflow (degenerate ties)
  }
  __syncthreads();

  if (s_fb) {
    // exact slow path: rebuild all keys, full block sort, rerun tiled NMS
    ulonglong2* skp = (ulonglong2*)sk;
#pragma unroll
    for (int j = 0; j < 4; ++j) skp[j * 512 + tid] = kr[j];
    __syncthreads();
    bitonic_sort_desc(sk, MM, tid);
    int cnt = tiled_nms(sk, Vtot, cbg, off_base, sbox, map, 0, tob, trb, tarea,
                        smask, sflag, knew, kept_ob, kept_raw, kept_area,
                        kept_key, &s_nnew, tid);
    if (tid == 0) s_cnt = cnt;
    __syncthreads();
  }

  // output: rows [0,cnt) from kept arrays, rows [cnt,100) zeros. Covers all
  // 100 rows incl. the stash slots (scores rows 96..99).
  int cnt = s_cnt;
  if (tid < MAXDET) {
    float4 bx = make_float4(0.0f, 0.0f, 0.0f, 0.0f);
    float sc = 0.0f, lb = 0.0f, kp = 0.0f;
    if (tid < cnt) {
      unsigned long long key = kept_key[tid];
      int m = (int)(0xFFFFFFFFu - (unsigned)key);
      bx = kept_raw[tid];
      sc = __uint_as_float((unsigned)(key >> 32));
      lb = (float)((m & 1) + 1);
      kp = 1.0f;
    }
    float* obp = out + (size_t)b * MAXDET * 4 + (size_t)tid * 4;
    obp[0] = bx.x; obp[1] = bx.y; obp[2] = bx.z; obp[3] = bx.w;
    out[SCORE_OFF + b * MAXDET + tid] = sc;
    out[LABEL_OFF + b * MAXDET + tid] = lb;
    out[KEEP_OFF + b * MAXDET + tid] = kp;
  }
}

extern "C" void kernel_launch(void* const* d_in, const int* in_sizes, int n_in,
                              void* d_out, int out_size, void* d_ws, size_t ws_size,
                              hipStream_t stream) {
  const float* logits = (const float*)d_in[0];
  const float* rel = (const float*)d_in[1];
  const float* props = (const float*)d_in[2];
  const int* ph = (const int*)d_in[3];
  const int* pw = (const int*)d_in[4];
  float* out = (float*)d_out;

  // ws layout (400 KB):
  char* ws = (char*)d_ws;
  float4* cand_box = (float4*)ws;                                              // 256 KB
  unsigned long long* keys = (unsigned long long*)(ws + (size_t)BB * MM * 16); // 128 KB
  unsigned* hist_g = (unsigned*)(ws + (size_t)BB * MM * 16 + (size_t)BB * MM * 8); // 16 KB

  hipMemsetAsync(hist_g, 0, BB * 1024 * sizeof(unsigned), stream);
  decode_kernel<<<16, 512, 0, stream>>>(logits, rel, props, ph, pw, cand_box,
                                        keys, hist_g, out);
  nms_kernel<<<BB, 512, 0, stream>>>(cand_box, keys, hist_g, out);
}

// Round 7
// 96.112 us; speedup vs baseline: 1.1605x; 1.1605x over previous
//
#include <hip/hip_runtime.h>
#include <stdint.h>

#define BB 4
#define NN 2048
#define CC 3
#define MM (NN * (CC - 1)) /* 4096 */
#define MAXDET 100
#define SCORE_THR 0.05f
#define NMS_THR 0.5f
#define MIN_SIZE 0.01f
#define TTARGET 256 /* selection prefix size (scan depth ~115 on this data) */
#define SSKCAP 1024 /* mid-path sort buffer capacity */
#define TILE 128    /* NMS tile size */

// out layout: boxes[4,100,4] ++ scores[4,100] ++ labels[4,100] ++ keep[4,100]
#define SCORE_OFF (BB * MAXDET * 4)         /* 1600 */
#define LABEL_OFF (SCORE_OFF + BB * MAXDET) /* 2000 */
#define KEEP_OFF (LABEL_OFF + BB * MAXDET)  /* 2400 */
// per-image scratch stash (scores rows 96..99): decode writes, nms reads,
// then nms's output phase overwrites. Block-private, no races.
#define STASH(b, j) (SCORE_OFF + (b) * MAXDET + 96 + (j))

// Wave-local LDS sync (r4-validated): drains this wave's LDS ops + pins
// compiler scheduling. Sufficient when all exchanging threads are one wave.
__device__ __forceinline__ void wave_lds_sync() {
  __builtin_amdgcn_wave_barrier();
  __builtin_amdgcn_s_waitcnt(0xC07F); // vmcnt(63) expcnt(7) lgkmcnt(0)
  __builtin_amdgcn_wave_barrier();
}

// Exact reference IoU>thr test (validated absmax=0 across rounds 1-6).
__device__ __forceinline__ bool iou_gt(const float4 A, const float aA,
                                       const float4 B, const float aB) {
#pragma clang fp contract(off)
  float ltx = fmaxf(A.x, B.x), lty = fmaxf(A.y, B.y);
  float rbx = fminf(A.z, B.z), rby = fminf(A.w, B.w);
  float iw = fmaxf(rbx - ltx, 0.0f), ih = fmaxf(rby - lty, 0.0f);
  float inter = iw * ih;
  float denom = ((aA + aB) - inter) + 1e-7f;
  return inter / denom > NMS_THR;
}

// ---------------------------------------------------------------------------
// decode: one thread per proposal (8192 threads, 16 blocks). Writes candidate
// boxes + keys (key=0 for invalid), global score-bin histogram (1024 bins per
// image, pre-zeroed via hipMemsetAsync), and per-block coord max to the stash.
// FP arithmetic bitwise-identical to the validated rounds-1..6 path.
// ---------------------------------------------------------------------------
__global__ __launch_bounds__(512) void decode_kernel(const float* __restrict__ logits,
                                                     const float* __restrict__ rel,
                                                     const float* __restrict__ props,
                                                     const int* __restrict__ ph,
                                                     const int* __restrict__ pw,
                                                     float4* __restrict__ cand_box,
                                                     unsigned long long* __restrict__ keys,
                                                     unsigned* __restrict__ hist_g,
                                                     float* __restrict__ out) {
#pragma clang fp contract(off)
  __shared__ float red[512];
  int tid = threadIdx.x;
  int t = blockIdx.x * 512 + tid; // proposal index; block spans one image only
  int b = t >> 11;
  int n = t & 2047;
  float Hf = (float)ph[0];
  float Wf = (float)pw[0];

  const float* lg = logits + (size_t)t * CC;
  float l0 = lg[0], l1 = lg[1], l2 = lg[2];
  float mx = fmaxf(l0, fmaxf(l1, l2));
  float e0 = expf(l0 - mx), e1 = expf(l1 - mx), e2 = expf(l2 - mx);
  float ssum = (e0 + e1) + e2;

  float4 pr = ((const float4*)props)[t];
  float w = pr.z - pr.x, h = pr.w - pr.y;
  float cx = pr.x + 0.5f * w, cy = pr.y + 0.5f * h;
  const float4* rl = (const float4*)(rel + (size_t)t * 12);
  const float SCALE_CLAMP = 4.135166556742356f; // log(1000/16) as f32

  float lmax = 0.0f;
  for (int c = 1; c < CC; ++c) {
    float4 rv = rl[c];
    float score = (c == 1 ? e1 : e2) / ssum;
    float dx = rv.x / 10.0f;
    float dy = rv.y / 10.0f;
    float dw = fminf(rv.z / 5.0f, SCALE_CLAMP);
    float dh = fminf(rv.w / 5.0f, SCALE_CLAMP);
    float pcx = dx * w + cx;
    float pcy = dy * h + cy;
    float bw = expf(dw) * w;
    float bh = expf(dh) * h;
    float x1 = pcx - 0.5f * bw, y1 = pcy - 0.5f * bh;
    float x2 = pcx + 0.5f * bw, y2 = pcy + 0.5f * bh;
    x1 = fminf(fmaxf(x1, 0.0f), Wf);
    y1 = fminf(fmaxf(y1, 0.0f), Hf);
    x2 = fminf(fmaxf(x2, 0.0f), Wf);
    y2 = fminf(fmaxf(y2, 0.0f), Hf);

    // jnp.max(boxes) is over ALL candidate boxes (incl. invalid)
    lmax = fmaxf(lmax, fmaxf(fmaxf(x1, y1), fmaxf(x2, y2)));

    bool valid = (score > SCORE_THR) && (x2 - x1 >= MIN_SIZE) && (y2 - y1 >= MIN_SIZE);
    int m = n * (CC - 1) + (c - 1);
    cand_box[(size_t)b * MM + m] = make_float4(x1, y1, x2, y2);
    unsigned long long key = 0ull;
    if (valid) {
      unsigned sb = __float_as_uint(score);
      key = (((unsigned long long)sb) << 32) |
            (unsigned long long)(0xFFFFFFFFu - (unsigned)m);
      // bin = score bits[25:16]; monotone in score over (0.05,1] (bits[31:26]
      // constant). Validated rounds 3-6.
      atomicAdd(&hist_g[b * 1024 + ((sb >> 16) & 1023)], 1u);
    }
    keys[(size_t)b * MM + m] = key;
  }

  red[tid] = lmax;
  __syncthreads();
  for (int s2 = 256; s2 > 0; s2 >>= 1) {
    if (tid < s2) red[tid] = fmaxf(red[tid], red[tid + s2]);
    __syncthreads();
  }
  if (tid == 0) out[STASH(b, blockIdx.x & 3)] = red[0];
}

// ---------------------------------------------------------------------------
// Block-wide hybrid bitonic sort (mid/fallback paths; r4/r5-validated).
// 8 waves hide each other's LDS latency; stride<128 stages are wave-local.
// ---------------------------------------------------------------------------
__device__ void bitonic_sort_desc(unsigned long long* a, int P, int tid) {
  int prev_big = 1;
  for (int size = 2; size <= P; size <<= 1) {
    for (int stride = size >> 1; stride > 0; stride >>= 1) {
      int big = (stride >= 128);
      if (big | prev_big) __syncthreads(); else wave_lds_sync();
      for (int i = tid; i < (P >> 1); i += 512) {
        int lo = 2 * i - (i & (stride - 1));
        int hi = lo + stride;
        bool asc = ((lo & size) != 0);
        unsigned long long x = a[lo], y = a[hi];
        if ((x > y) == asc) { a[lo] = y; a[hi] = x; }
      }
      prev_big = big;
    }
  }
  __syncthreads();
}

// ---------------------------------------------------------------------------
// Register bitonic sort of exactly 512 elements, 1 element/thread (fast path).
// Element i lives in thread i's VGPR. stride<64 exchanges are intra-wave
// __shfl_xor (no LDS); the 6 stride>=64 stages round-trip LDS with
// alternating buffers (one barrier each). Descending; zeros sink. Result
// written back to a[0..511]. All 512 threads must call.
// ---------------------------------------------------------------------------
__device__ void bitonic_sort_desc_reg512(unsigned long long* a,
                                         unsigned long long* xbuf0,
                                         unsigned long long* xbuf1,
                                         int T, int tid) {
  unsigned long long v = (tid < T) ? a[tid] : 0ull;
  int xb = 0;
  for (int size = 2; size <= 512; size <<= 1) {
    for (int stride = size >> 1; stride > 0; stride >>= 1) {
      unsigned long long o;
      if (stride < 64) {
        o = __shfl_xor(v, stride);
      } else {
        unsigned long long* buf = xb ? xbuf1 : xbuf0;
        __syncthreads(); // protect buf reuse (alternation gives 2-stage gap)
        buf[tid] = v;
        __syncthreads();
        o = buf[tid ^ stride];
        xb ^= 1;
      }
      bool is_lo = (tid & stride) == 0;
      bool asc = (tid & size) != 0; // same for both partners (stride < size)
      bool take_min = (asc == is_lo);
      bool o_less = (o < v);
      unsigned long long mn = o_less ? o : v;
      unsigned long long mx = o_less ? v : o;
      v = take_min ? mn : mx;
    }
  }
  __syncthreads();
  a[tid] = v;
  __syncthreads();
}

// ---------------------------------------------------------------------------
// Mask-based tiled greedy NMS over a sorted key array (r5/r6-validated, exact).
// use_map: boxes come from LDS (sboxall[map[m]]) instead of global cbg[m].
// Whole block must call (contains barriers). Returns final kept count.
// ---------------------------------------------------------------------------
__device__ int tiled_nms(const unsigned long long* keys_s, int count,
                         const float4* __restrict__ cbg, float off_base,
                         const float4* sboxall, const unsigned short* map, int use_map,
                         float4* tob, float4* trb, float* tarea,
                         ulonglong2* smask, int* sflag, int* knew,
                         float4* kept_ob, float4* kept_raw, float* kept_area,
                         unsigned long long* kept_key, int* s_nnew, int tid) {
#pragma clang fp contract(off)
  int wv = tid >> 6, lane = tid & 63;
  int cnt = 0;
  for (int base = 0; base < count && cnt < MAXDET; base += TILE) {
    int tsz = (count - base < TILE) ? (count - base) : TILE;
    // gather tile: raw box, offset box, area (exact offset arithmetic)
    if (tid < tsz) {
      unsigned long long key = keys_s[base + tid];
      int m = (int)(0xFFFFFFFFu - (unsigned)key);
      float4 bx = use_map ? sboxall[map[m]] : cbg[m];
      int lbl = (m & 1) + 1;
      float off = (float)lbl * off_base;
      float4 ob = make_float4(bx.x + off, bx.y + off, bx.z + off, bx.w + off);
      tob[tid] = ob;
      trb[tid] = bx;
      tarea[tid] = (ob.z - ob.x) * (ob.w - ob.y);
    }
    __syncthreads();

    // per-lane register copies (invariant across rows of this tile)
    float4 bi0 = tob[lane];
    float ai0 = tarea[lane];
    float4 bi1 = tob[lane + 64];
    float ai1 = tarea[lane + 64];
    float4 kb0 = kept_ob[(lane < cnt) ? lane : 0];
    float ka0 = kept_area[(lane < cnt) ? lane : 0];
    float4 kb1 = kept_ob[(lane + 64 < cnt) ? lane + 64 : 0];
    float ka1 = kept_area[(lane + 64 < cnt) ? lane + 64 : 0];

    // matrix phase: wave wv handles rows j = wv, wv+8, ...
    for (int j = wv; j < tsz; j += 8) {
      float4 aj = tob[j];
      float aaj = tarea[j];
      unsigned long long w0 = 0ull, w1 = 0ull;
      if (j < 63) {
        bool p = (lane > j) && (lane < tsz) && iou_gt(aj, aaj, bi0, ai0);
        w0 = __ballot(p);
      }
      if (j < 127) {
        int i = lane + 64;
        bool p = (i > j) && (i < tsz) && iou_gt(aj, aaj, bi1, ai1);
        w1 = __ballot(p);
      }
      bool s = false;
      if (cnt > 0) {
        if (lane < cnt && iou_gt(kb0, ka0, aj, aaj)) s = true;
        if (cnt > 64 && lane + 64 < cnt && iou_gt(kb1, ka1, aj, aaj)) s = true;
      }
      int anyk = __any(s);
      if (lane == 0) {
        smask[j].x = w0;
        smask[j].y = w1;
        sflag[j] = anyk;
      }
    }
    __syncthreads();

    // serial bit reduction on wave 0: rows in lane regs, fetched via shfl.
    if (tid < 64) {
      int iA = 2 * lane, iB = 2 * lane + 1;
      ulonglong2 rA = smask[(iA < tsz) ? iA : 0];
      ulonglong2 rB = smask[(iB < tsz) ? iB : 0];
      int fA = sflag[(iA < tsz) ? iA : 0];
      int fB = sflag[(iB < tsz) ? iB : 0];
      unsigned long long r0 = 0ull, r1 = 0ull;
      int c = cnt, nk = 0;
      for (int j = 0; j < tsz; ++j) {
        int src = j >> 1;
        unsigned long long m0 = __shfl((j & 1) ? rB.x : rA.x, src);
        unsigned long long m1 = __shfl((j & 1) ? rB.y : rA.y, src);
        int fl = __shfl((j & 1) ? fB : fA, src);
        bool rem = (j < 64) ? ((r0 >> j) & 1ull) : ((r1 >> (j - 64)) & 1ull);
        if (!rem && !fl) {
          if (lane == 0) knew[nk] = j;
          nk++;
          c++;
          r0 |= m0;
          r1 |= m1;
          if (c >= MAXDET) break;
        }
      }
      if (lane == 0) *s_nnew = nk;
    }
    __syncthreads();

    // append new keeps (parallel)
    int nnew = *s_nnew;
    if (tid < nnew) {
      int j = knew[tid];
      kept_ob[cnt + tid] = tob[j];
      kept_raw[cnt + tid] = trb[j];
      kept_area[cnt + tid] = tarea[j];
      kept_key[cnt + tid] = keys_s[base + j];
    }
    cnt += nnew;
    __syncthreads();
  }
  return cnt;
}

// ---------------------------------------------------------------------------
// nms_kernel: one block per image.
//  wave0 loads precomputed histogram + suffix-scans threshold, all waves load
//  keys -> ballot-compaction with inline coalesced box staging into LDS
//  (map[m]->pos) -> register shfl bitonic sort (T<=512, 8 waves, no LDS in
//  intra-wave stages) -> tiled NMS (LDS-only gathers). Mid path: T in
//  (512,1024] -> 8-wave hybrid LDS sort. Fallbacks: T>SSKCAP or prefix
//  insufficient -> full 4096 block sort + tiled NMS w/ global gathers.
// ---------------------------------------------------------------------------
__global__ __launch_bounds__(512) void nms_kernel(const float4* __restrict__ cand_box,
                                                  const unsigned long long* __restrict__ keys,
                                                  const unsigned* __restrict__ hist_g,
                                                  float* __restrict__ out) {
#pragma clang fp contract(off)
  __shared__ __align__(16) unsigned long long sk[MM];      // 32 KB (fallback + xbuf)
  __shared__ __align__(16) unsigned long long ssk[SSKCAP]; // 8 KB selected keys
  __shared__ __align__(16) float4 sbox[SSKCAP];            // 16 KB staged boxes
  __shared__ unsigned short map[MM];                       // 8 KB m -> sbox pos
  __shared__ __align__(16) float4 tob[TILE];
  __shared__ __align__(16) float4 trb[TILE];
  __shared__ float tarea[TILE];
  __shared__ __align__(16) ulonglong2 smask[TILE];
  __shared__ int sflag[TILE];
  __shared__ int knew[TILE];
  __shared__ float4 kept_ob[MAXDET];
  __shared__ float4 kept_raw[MAXDET];
  __shared__ float kept_area[MAXDET];
  __shared__ unsigned long long kept_key[MAXDET];
  __shared__ int s_scnt, s_thr, s_vtot, s_cnt, s_fb, s_nnew;

  int b = blockIdx.x;
  int tid = threadIdx.x;
  int lane = tid & 63;
  const float4* cbg = cand_box + (size_t)b * MM;

  // coalesced key loads into registers (all waves, issued first)
  const ulonglong2* kg = (const ulonglong2*)(keys + (size_t)b * MM);
  ulonglong2 kr[4];
#pragma unroll
  for (int j = 0; j < 4; ++j) kr[j] = kg[j * 512 + tid];

  if (tid == 0) { s_scnt = 0; s_fb = 0; s_cnt = 0; }
  // per-image max from decode stash -> offset base (reference: max(boxes)+1)
  float m01 = fmaxf(out[STASH(b, 0)], out[STASH(b, 1)]);
  float m23 = fmaxf(out[STASH(b, 2)], out[STASH(b, 3)]);
  float off_base = fmaxf(m01, m23) + 1.0f;

  // wave 0: load this image's 1024-bin histogram (coalesced 4 KB) and
  // suffix-scan for the threshold bin (largest bin with suffix >= TTARGET).
  if (tid < 64) {
    const unsigned* hg = hist_g + b * 1024 + tid * 16;
    unsigned own[16];
#pragma unroll
    for (int i = 0; i < 16; ++i) own[i] = hg[i];
    unsigned psum = 0;
#pragma unroll
    for (int i = 0; i < 16; ++i) psum += own[i];
    unsigned s = psum;
    for (int d = 1; d < 64; d <<= 1) {
      unsigned o = __shfl_down(s, d);
      if (tid + d < 64) s += o;
    }
    unsigned after = s - psum;
    int best = -1;
    unsigned run = after;
#pragma unroll
    for (int i = 15; i >= 0; --i) {
      run += own[i];
      if (best < 0 && run >= TTARGET) best = tid * 16 + i;
    }
    int gb = best;
    for (int d = 1; d < 64; d <<= 1) {
      int o = __shfl_down(gb, d);
      if (tid + d < 64) gb = (o > gb) ? o : gb;
    }
    if (tid == 0) {
      s_thr = (gb < 0) ? 0 : gb;
      s_vtot = (int)s;
    }
  }
  __syncthreads();
  int thr = s_thr;
  int Vtot = s_vtot;

  // ballot-compaction of selected keys into ssk, with inline coalesced box
  // staging: thread tid owns m0=1024j+2tid and m0+1; box reads are contiguous
  // across the wave. map[m]=pos enables LDS-only tile gathers later.
#pragma unroll
  for (int j = 0; j < 4; ++j) {
    int m0 = 1024 * j + 2 * tid;
    float4 b0 = cbg[m0];
    float4 b1 = cbg[m0 + 1];
#pragma unroll
    for (int half = 0; half < 2; ++half) {
      unsigned long long key = half ? kr[j].y : kr[j].x;
      unsigned hik = (unsigned)(key >> 32);
      bool pred = (hik != 0u) && ((int)((hik >> 16) & 1023) >= thr);
      unsigned long long mask = __ballot(pred);
      int ofs = __popcll(mask & ((1ull << lane) - 1ull));
      int basea = 0;
      if (lane == 0 && mask) basea = atomicAdd(&s_scnt, (int)__popcll(mask));
      basea = __shfl(basea, 0);
      if (pred) {
        int pos = basea + ofs;
        if (pos < SSKCAP) {
          ssk[pos] = key;
          sbox[pos] = half ? b1 : b0;
          map[m0 + half] = (unsigned short)pos;
        }
      }
    }
  }
  __syncthreads();
  int T = s_scnt;

  if (T <= SSKCAP) {
    if (T <= 512) {
      // fast path: register shfl bitonic over exactly 512 slots
      bitonic_sort_desc_reg512(ssk, sk, sk + 512, T, tid);
    } else {
      // mid path: 8-wave hybrid LDS sort at P<=1024
      int P = 1;
      while (P < T) P <<= 1;
      for (int i = T + tid; i < P; i += 512) ssk[i] = 0ull;
      __syncthreads();
      bitonic_sort_desc(ssk, P, tid);
    }
    int cnt = tiled_nms(ssk, T, cbg, off_base, sbox, map, 1, tob, trb, tarea,
                        smask, sflag, knew, kept_ob, kept_raw, kept_area,
                        kept_key, &s_nnew, tid);
    if (tid == 0) {
      s_cnt = cnt;
      s_fb = (cnt < MAXDET && T < Vtot) ? 1 : 0; // prefix insufficient
    }
  } else {
    if (tid == 0) s_fb = 1; // selection overflow (degenerate ties)
  }
  __syncthreads();

  if (s_fb) {
    // exact slow path: rebuild all keys, full block sort, rerun tiled NMS
    ulonglong2* skp = (ulonglong2*)sk;
#pragma unroll
    for (int j = 0; j < 4; ++j) skp[j * 512 + tid] = kr[j];
    __syncthreads();
    bitonic_sort_desc(sk, MM, tid);
    int cnt = tiled_nms(sk, Vtot, cbg, off_base, sbox, map, 0, tob, trb, tarea,
                        smask, sflag, knew, kept_ob, kept_raw, kept_area,
                        kept_key, &s_nnew, tid);
    if (tid == 0) s_cnt = cnt;
    __syncthreads();
  }

  // output: rows [0,cnt) from kept arrays, rows [cnt,100) zeros. Covers all
  // 100 rows incl. the stash slots (scores rows 96..99).
  int cnt = s_cnt;
  if (tid < MAXDET) {
    float4 bx = make_float4(0.0f, 0.0f, 0.0f, 0.0f);
    float sc = 0.0f, lb = 0.0f, kp = 0.0f;
    if (tid < cnt) {
      unsigned long long key = kept_key[tid];
      int m = (int)(0xFFFFFFFFu - (unsigned)key);
      bx = kept_raw[tid];
      sc = __uint_as_float((unsigned)(key >> 32));
      lb = (float)((m & 1) + 1);
      kp = 1.0f;
    }
    float* obp = out + (size_t)b * MAXDET * 4 + (size_t)tid * 4;
    obp[0] = bx.x; obp[1] = bx.y; obp[2] = bx.z; obp[3] = bx.w;
    out[SCORE_OFF + b * MAXDET + tid] = sc;
    out[LABEL_OFF + b * MAXDET + tid] = lb;
    out[KEEP_OFF + b * MAXDET + tid] = kp;
  }
}

extern "C" void kernel_launch(void* const* d_in, const int* in_sizes, int n_in,
                              void* d_out, int out_size, void* d_ws, size_t ws_size,
                              hipStream_t stream) {
  const float* logits = (const float*)d_in[0];
  const float* rel = (const float*)d_in[1];
  const float* props = (const float*)d_in[2];
  const int* ph = (const int*)d_in[3];
  const int* pw = (const int*)d_in[4];
  float* out = (float*)d_out;

  // ws layout (400 KB):
  char* ws = (char*)d_ws;
  float4* cand_box = (float4*)ws;                                              // 256 KB
  unsigned long long* keys = (unsigned long long*)(ws + (size_t)BB * MM * 16); // 128 KB
  unsigned* hist_g = (unsigned*)(ws + (size_t)BB * MM * 16 + (size_t)BB * MM * 8); // 16 KB

  hipMemsetAsync(hist_g, 0, BB * 1024 * sizeof(unsigned), stream);
  decode_kernel<<<16, 512, 0, stream>>>(logits, rel, props, ph, pw, cand_box,
                                        keys, hist_g, out);
  nms_kernel<<<BB, 512, 0, stream>>>(cand_box, keys, hist_g, out);
}

// Round 8
// 94.718 us; speedup vs baseline: 1.1776x; 1.0147x over previous
//
#include <hip/hip_runtime.h>
#include <stdint.h>

#define BB 4
#define NN 2048
#define CC 3
#define MM (NN * (CC - 1)) /* 4096 */
#define MAXDET 100
#define SCORE_THR 0.05f
#define NMS_THR 0.5f
#define MIN_SIZE 0.01f
#define TTARGET 256 /* selection prefix size (scan depth ~115 on this data) */
#define SSKCAP 1024 /* mid-path sort buffer capacity */
#define TILE 128    /* NMS tile size */

// out layout: boxes[4,100,4] ++ scores[4,100] ++ labels[4,100] ++ keep[4,100]
#define SCORE_OFF (BB * MAXDET * 4)         /* 1600 */
#define LABEL_OFF (SCORE_OFF + BB * MAXDET) /* 2000 */
#define KEEP_OFF (LABEL_OFF + BB * MAXDET)  /* 2400 */
// per-image scratch stash (scores rows 96..99): decode writes, nms reads,
// then nms's output phase overwrites. Block-private, no races.
#define STASH(b, j) (SCORE_OFF + (b) * MAXDET + 96 + (j))

// Wave-local LDS sync (r4-validated).
__device__ __forceinline__ void wave_lds_sync() {
  __builtin_amdgcn_wave_barrier();
  __builtin_amdgcn_s_waitcnt(0xC07F); // vmcnt(63) expcnt(7) lgkmcnt(0)
  __builtin_amdgcn_wave_barrier();
}

// Exact reference IoU>thr test (validated absmax=0 across rounds 1-7).
__device__ __forceinline__ bool iou_gt(const float4 A, const float aA,
                                       const float4 B, const float aB) {
#pragma clang fp contract(off)
  float ltx = fmaxf(A.x, B.x), lty = fmaxf(A.y, B.y);
  float rbx = fminf(A.z, B.z), rby = fminf(A.w, B.w);
  float iw = fmaxf(rbx - ltx, 0.0f), ih = fmaxf(rby - lty, 0.0f);
  float inter = iw * ih;
  float denom = ((aA + aB) - inter) + 1e-7f;
  return inter / denom > NMS_THR;
}

// ---------------------------------------------------------------------------
// decode: one thread per proposal (8192 threads, 16 blocks). Writes candidate
// boxes + keys (key=0 for invalid), a per-BLOCK score-bin histogram (private
// global slot -> no pre-zero memset needed), and per-block coord max stash.
// FP arithmetic bitwise-identical to the validated rounds-1..7 path.
// ---------------------------------------------------------------------------
__global__ __launch_bounds__(512) void decode_kernel(const float* __restrict__ logits,
                                                     const float* __restrict__ rel,
                                                     const float* __restrict__ props,
                                                     const int* __restrict__ ph,
                                                     const int* __restrict__ pw,
                                                     float4* __restrict__ cand_box,
                                                     unsigned long long* __restrict__ keys,
                                                     unsigned* __restrict__ hist_g,
                                                     float* __restrict__ out) {
#pragma clang fp contract(off)
  __shared__ float red[512];
  __shared__ unsigned lhist[1024];
  int tid = threadIdx.x;
  int t = blockIdx.x * 512 + tid; // proposal index; block spans one image only
  int b = t >> 11;
  int n = t & 2047;
  float Hf = (float)ph[0];
  float Wf = (float)pw[0];

  lhist[tid] = 0u;
  lhist[tid + 512] = 0u;
  __syncthreads();

  const float* lg = logits + (size_t)t * CC;
  float l0 = lg[0], l1 = lg[1], l2 = lg[2];
  float mx = fmaxf(l0, fmaxf(l1, l2));
  float e0 = expf(l0 - mx), e1 = expf(l1 - mx), e2 = expf(l2 - mx);
  float ssum = (e0 + e1) + e2;

  float4 pr = ((const float4*)props)[t];
  float w = pr.z - pr.x, h = pr.w - pr.y;
  float cx = pr.x + 0.5f * w, cy = pr.y + 0.5f * h;
  const float4* rl = (const float4*)(rel + (size_t)t * 12);
  const float SCALE_CLAMP = 4.135166556742356f; // log(1000/16) as f32

  float lmax = 0.0f;
  for (int c = 1; c < CC; ++c) {
    float4 rv = rl[c];
    float score = (c == 1 ? e1 : e2) / ssum;
    float dx = rv.x / 10.0f;
    float dy = rv.y / 10.0f;
    float dw = fminf(rv.z / 5.0f, SCALE_CLAMP);
    float dh = fminf(rv.w / 5.0f, SCALE_CLAMP);
    float pcx = dx * w + cx;
    float pcy = dy * h + cy;
    float bw = expf(dw) * w;
    float bh = expf(dh) * h;
    float x1 = pcx - 0.5f * bw, y1 = pcy - 0.5f * bh;
    float x2 = pcx + 0.5f * bw, y2 = pcy + 0.5f * bh;
    x1 = fminf(fmaxf(x1, 0.0f), Wf);
    y1 = fminf(fmaxf(y1, 0.0f), Hf);
    x2 = fminf(fmaxf(x2, 0.0f), Wf);
    y2 = fminf(fmaxf(y2, 0.0f), Hf);

    // jnp.max(boxes) is over ALL candidate boxes (incl. invalid)
    lmax = fmaxf(lmax, fmaxf(fmaxf(x1, y1), fmaxf(x2, y2)));

    bool valid = (score > SCORE_THR) && (x2 - x1 >= MIN_SIZE) && (y2 - y1 >= MIN_SIZE);
    int m = n * (CC - 1) + (c - 1);
    cand_box[(size_t)b * MM + m] = make_float4(x1, y1, x2, y2);
    unsigned long long key = 0ull;
    if (valid) {
      unsigned sb = __float_as_uint(score);
      key = (((unsigned long long)sb) << 32) |
            (unsigned long long)(0xFFFFFFFFu - (unsigned)m);
      // bin = score bits[25:16]; monotone in score over (0.05,1] (bits[31:26]
      // constant). Validated rounds 3-7.
      atomicAdd(&lhist[(sb >> 16) & 1023], 1u);
    }
    keys[(size_t)b * MM + m] = key;
  }

  red[tid] = lmax;
  __syncthreads(); // also fences lhist atomics
  for (int s2 = 256; s2 > 0; s2 >>= 1) {
    if (tid < s2) red[tid] = fmaxf(red[tid], red[tid + s2]);
    __syncthreads();
  }
  if (tid == 0) out[STASH(b, blockIdx.x & 3)] = red[0];

  // flush per-block histogram to its private global slot (coalesced)
  hist_g[blockIdx.x * 1024 + tid] = lhist[tid];
  hist_g[blockIdx.x * 1024 + tid + 512] = lhist[tid + 512];
}

// ---------------------------------------------------------------------------
// Block-wide hybrid bitonic sort (mid/fallback paths; r4/r5-validated).
// ---------------------------------------------------------------------------
__device__ void bitonic_sort_desc(unsigned long long* a, int P, int tid) {
  int prev_big = 1;
  for (int size = 2; size <= P; size <<= 1) {
    for (int stride = size >> 1; stride > 0; stride >>= 1) {
      int big = (stride >= 128);
      if (big | prev_big) __syncthreads(); else wave_lds_sync();
      for (int i = tid; i < (P >> 1); i += 512) {
        int lo = 2 * i - (i & (stride - 1));
        int hi = lo + stride;
        bool asc = ((lo & size) != 0);
        unsigned long long x = a[lo], y = a[hi];
        if ((x > y) == asc) { a[lo] = y; a[hi] = x; }
      }
      prev_big = big;
    }
  }
  __syncthreads();
}

// ---------------------------------------------------------------------------
// Register bitonic sort of exactly 512 elements, 1/thread (r7-validated).
// ---------------------------------------------------------------------------
__device__ void bitonic_sort_desc_reg512(unsigned long long* a,
                                         unsigned long long* xbuf0,
                                         unsigned long long* xbuf1,
                                         int T, int tid) {
  unsigned long long v = (tid < T) ? a[tid] : 0ull;
  int xb = 0;
  for (int size = 2; size <= 512; size <<= 1) {
    for (int stride = size >> 1; stride > 0; stride >>= 1) {
      unsigned long long o;
      if (stride < 64) {
        o = __shfl_xor(v, stride);
      } else {
        unsigned long long* buf = xb ? xbuf1 : xbuf0;
        __syncthreads();
        buf[tid] = v;
        __syncthreads();
        o = buf[tid ^ stride];
        xb ^= 1;
      }
      bool is_lo = (tid & stride) == 0;
      bool asc = (tid & size) != 0;
      bool take_min = (asc == is_lo);
      bool o_less = (o < v);
      unsigned long long mn = o_less ? o : v;
      unsigned long long mx = o_less ? v : o;
      v = take_min ? mn : mx;
    }
  }
  __syncthreads();
  a[tid] = v;
  __syncthreads();
}

// ---------------------------------------------------------------------------
// Mask-based tiled greedy NMS (exact; r5-r7 validated logic). NEW reduction:
// sflag folded into the initial suppressed bitmap via ballots; row masks read
// from LDS with uniform broadcast addresses through a 4-deep prefetch ring —
// per-iteration cost ~bit-test + 2 u64 ORs instead of five dependent shfls.
// Whole block must call (contains barriers). Returns final kept count.
// ---------------------------------------------------------------------------
__device__ int tiled_nms(const unsigned long long* keys_s, int count,
                         const float4* __restrict__ cbg, float off_base,
                         const float4* sboxall, const unsigned short* map, int use_map,
                         float4* tob, float4* trb, float* tarea,
                         ulonglong2* smask, int* sflag, int* knew,
                         float4* kept_ob, float4* kept_raw, float* kept_area,
                         unsigned long long* kept_key, int* s_nnew, int tid) {
#pragma clang fp contract(off)
  int wv = tid >> 6, lane = tid & 63;
  int cnt = 0;
  for (int base = 0; base < count && cnt < MAXDET; base += TILE) {
    int tsz = (count - base < TILE) ? (count - base) : TILE;
    // gather tile: raw box, offset box, area (exact offset arithmetic)
    if (tid < tsz) {
      unsigned long long key = keys_s[base + tid];
      int m = (int)(0xFFFFFFFFu - (unsigned)key);
      float4 bx = use_map ? sboxall[map[m]] : cbg[m];
      int lbl = (m & 1) + 1;
      float off = (float)lbl * off_base;
      float4 ob = make_float4(bx.x + off, bx.y + off, bx.z + off, bx.w + off);
      tob[tid] = ob;
      trb[tid] = bx;
      tarea[tid] = (ob.z - ob.x) * (ob.w - ob.y);
    }
    __syncthreads();

    // per-lane register copies (invariant across rows of this tile)
    float4 bi0 = tob[lane];
    float ai0 = tarea[lane];
    float4 bi1 = tob[lane + 64];
    float ai1 = tarea[lane + 64];
    float4 kb0 = kept_ob[(lane < cnt) ? lane : 0];
    float ka0 = kept_area[(lane < cnt) ? lane : 0];
    float4 kb1 = kept_ob[(lane + 64 < cnt) ? lane + 64 : 0];
    float ka1 = kept_area[(lane + 64 < cnt) ? lane + 64 : 0];

    // matrix phase: wave wv handles rows j = wv, wv+8, ...
    for (int j = wv; j < tsz; j += 8) {
      float4 aj = tob[j];
      float aaj = tarea[j];
      unsigned long long w0 = 0ull, w1 = 0ull;
      if (j < 63) {
        bool p = (lane > j) && (lane < tsz) && iou_gt(aj, aaj, bi0, ai0);
        w0 = __ballot(p);
      }
      if (j < 127) {
        int i = lane + 64;
        bool p = (i > j) && (i < tsz) && iou_gt(aj, aaj, bi1, ai1);
        w1 = __ballot(p);
      }
      bool s = false;
      if (cnt > 0) {
        if (lane < cnt && iou_gt(kb0, ka0, aj, aaj)) s = true;
        if (cnt > 64 && lane + 64 < cnt && iou_gt(kb1, ka1, aj, aaj)) s = true;
      }
      int anyk = __any(s);
      if (lane == 0) {
        smask[j].x = w0;
        smask[j].y = w1;
        sflag[j] = anyk;
      }
    }
    __syncthreads();

    // serial bit reduction on wave 0 — uniform across lanes, rows broadcast
    // from LDS via a 4-deep prefetch ring (no shfl chains).
    if (tid < 64) {
      bool f0 = (lane < tsz) && (sflag[lane] != 0);
      unsigned long long remv0 = __ballot(f0);
      bool f1 = (lane + 64 < tsz) && (sflag[lane + 64] != 0);
      unsigned long long remv1 = __ballot(f1);
      ulonglong2 pre[4];
#pragma unroll
      for (int k = 0; k < 4; ++k) pre[k] = smask[(k < tsz) ? k : 0];
      int c = cnt, nk = 0;
      for (int j = 0; j < tsz; ++j) {
        ulonglong2 row = pre[j & 3];
        int nxt = j + 4;
        pre[j & 3] = smask[(nxt < tsz) ? nxt : 0];
        bool rem = (j < 64) ? (((remv0 >> j) & 1ull) != 0ull)
                            : (((remv1 >> (j - 64)) & 1ull) != 0ull);
        if (!rem) {
          if (lane == 0) knew[nk] = j;
          nk++;
          c++;
          remv0 |= row.x;
          remv1 |= row.y;
          if (c >= MAXDET) break;
        }
      }
      if (lane == 0) *s_nnew = nk;
    }
    __syncthreads();

    // append new keeps (parallel)
    int nnew = *s_nnew;
    if (tid < nnew) {
      int j = knew[tid];
      kept_ob[cnt + tid] = tob[j];
      kept_raw[cnt + tid] = trb[j];
      kept_area[cnt + tid] = tarea[j];
      kept_key[cnt + tid] = keys_s[base + j];
    }
    cnt += nnew;
    __syncthreads();
  }
  return cnt;
}

// ---------------------------------------------------------------------------
// nms_kernel: one block per image (structure r7-validated).
// ---------------------------------------------------------------------------
__global__ __launch_bounds__(512) void nms_kernel(const float4* __restrict__ cand_box,
                                                  const unsigned long long* __restrict__ keys,
                                                  const unsigned* __restrict__ hist_g,
                                                  float* __restrict__ out) {
#pragma clang fp contract(off)
  __shared__ __align__(16) unsigned long long sk[MM];      // 32 KB (fallback + xbuf)
  __shared__ __align__(16) unsigned long long ssk[SSKCAP]; // 8 KB selected keys
  __shared__ __align__(16) float4 sbox[SSKCAP];            // 16 KB staged boxes
  __shared__ unsigned short map[MM];                       // 8 KB m -> sbox pos
  __shared__ __align__(16) float4 tob[TILE];
  __shared__ __align__(16) float4 trb[TILE];
  __shared__ float tarea[TILE];
  __shared__ __align__(16) ulonglong2 smask[TILE];
  __shared__ int sflag[TILE];
  __shared__ int knew[TILE];
  __shared__ float4 kept_ob[MAXDET];
  __shared__ float4 kept_raw[MAXDET];
  __shared__ float kept_area[MAXDET];
  __shared__ unsigned long long kept_key[MAXDET];
  __shared__ int s_scnt, s_thr, s_vtot, s_cnt, s_fb, s_nnew;

  int b = blockIdx.x;
  int tid = threadIdx.x;
  int lane = tid & 63;
  const float4* cbg = cand_box + (size_t)b * MM;

  // coalesced key loads into registers (all waves, issued first)
  const ulonglong2* kg = (const ulonglong2*)(keys + (size_t)b * MM);
  ulonglong2 kr[4];
#pragma unroll
  for (int j = 0; j < 4; ++j) kr[j] = kg[j * 512 + tid];

  if (tid == 0) { s_scnt = 0; s_fb = 0; s_cnt = 0; }
  // per-image max from decode stash -> offset base (reference: max(boxes)+1)
  float m01 = fmaxf(out[STASH(b, 0)], out[STASH(b, 1)]);
  float m23 = fmaxf(out[STASH(b, 2)], out[STASH(b, 3)]);
  float off_base = fmaxf(m01, m23) + 1.0f;

  // wave 0: sum the image's 4 per-block histograms and suffix-scan for the
  // threshold bin (largest bin with suffix >= TTARGET).
  if (tid < 64) {
    const unsigned* hg = hist_g + (b * 4) * 1024 + tid * 16;
    unsigned own[16];
#pragma unroll
    for (int i = 0; i < 16; ++i)
      own[i] = hg[i] + hg[1024 + i] + hg[2048 + i] + hg[3072 + i];
    unsigned psum = 0;
#pragma unroll
    for (int i = 0; i < 16; ++i) psum += own[i];
    unsigned s = psum;
    for (int d = 1; d < 64; d <<= 1) {
      unsigned o = __shfl_down(s, d);
      if (tid + d < 64) s += o;
    }
    unsigned after = s - psum;
    int best = -1;
    unsigned run = after;
#pragma unroll
    for (int i = 15; i >= 0; --i) {
      run += own[i];
      if (best < 0 && run >= TTARGET) best = tid * 16 + i;
    }
    int gb = best;
    for (int d = 1; d < 64; d <<= 1) {
      int o = __shfl_down(gb, d);
      if (tid + d < 64) gb = (o > gb) ? o : gb;
    }
    if (tid == 0) {
      s_thr = (gb < 0) ? 0 : gb;
      s_vtot = (int)s;
    }
  }
  __syncthreads();
  int thr = s_thr;
  int Vtot = s_vtot;

  // ballot-compaction of selected keys into ssk, with inline coalesced box
  // staging (map[m]=pos enables LDS-only tile gathers later).
#pragma unroll
  for (int j = 0; j < 4; ++j) {
    int m0 = 1024 * j + 2 * tid;
    float4 b0 = cbg[m0];
    float4 b1 = cbg[m0 + 1];
#pragma unroll
    for (int half = 0; half < 2; ++half) {
      unsigned long long key = half ? kr[j].y : kr[j].x;
      unsigned hik = (unsigned)(key >> 32);
      bool pred = (hik != 0u) && ((int)((hik >> 16) & 1023) >= thr);
      unsigned long long mask = __ballot(pred);
      int ofs = __popcll(mask & ((1ull << lane) - 1ull));
      int basea = 0;
      if (lane == 0 && mask) basea = atomicAdd(&s_scnt, (int)__popcll(mask));
      basea = __shfl(basea, 0);
      if (pred) {
        int pos = basea + ofs;
        if (pos < SSKCAP) {
          ssk[pos] = key;
          sbox[pos] = half ? b1 : b0;
          map[m0 + half] = (unsigned short)pos;
        }
      }
    }
  }
  __syncthreads();
  int T = s_scnt;

  if (T <= SSKCAP) {
    if (T <= 512) {
      bitonic_sort_desc_reg512(ssk, sk, sk + 512, T, tid);
    } else {
      int P = 1;
      while (P < T) P <<= 1;
      for (int i = T + tid; i < P; i += 512) ssk[i] = 0ull;
      __syncthreads();
      bitonic_sort_desc(ssk, P, tid);
    }
    int cnt = tiled_nms(ssk, T, cbg, off_base, sbox, map, 1, tob, trb, tarea,
                        smask, sflag, knew, kept_ob, kept_raw, kept_area,
                        kept_key, &s_nnew, tid);
    if (tid == 0) {
      s_cnt = cnt;
      s_fb = (cnt < MAXDET && T < Vtot) ? 1 : 0; // prefix insufficient
    }
  } else {
    if (tid == 0) s_fb = 1; // selection overflow (degenerate ties)
  }
  __syncthreads();

  if (s_fb) {
    // exact slow path: rebuild all keys, full block sort, rerun tiled NMS
    ulonglong2* skp = (ulonglong2*)sk;
#pragma unroll
    for (int j = 0; j < 4; ++j) skp[j * 512 + tid] = kr[j];
    __syncthreads();
    bitonic_sort_desc(sk, MM, tid);
    int cnt = tiled_nms(sk, Vtot, cbg, off_base, sbox, map, 0, tob, trb, tarea,
                        smask, sflag, knew, kept_ob, kept_raw, kept_area,
                        kept_key, &s_nnew, tid);
    if (tid == 0) s_cnt = cnt;
    __syncthreads();
  }

  // output: rows [0,cnt) from kept arrays, rows [cnt,100) zeros. Covers all
  // 100 rows incl. the stash slots (scores rows 96..99).
  int cnt = s_cnt;
  if (tid < MAXDET) {
    float4 bx = make_float4(0.0f, 0.0f, 0.0f, 0.0f);
    float sc = 0.0f, lb = 0.0f, kp = 0.0f;
    if (tid < cnt) {
      unsigned long long key = kept_key[tid];
      int m = (int)(0xFFFFFFFFu - (unsigned)key);
      bx = kept_raw[tid];
      sc = __uint_as_float((unsigned)(key >> 32));
      lb = (float)((m & 1) + 1);
      kp = 1.0f;
    }
    float* obp = out + (size_t)b * MAXDET * 4 + (size_t)tid * 4;
    obp[0] = bx.x; obp[1] = bx.y; obp[2] = bx.z; obp[3] = bx.w;
    out[SCORE_OFF + b * MAXDET + tid] = sc;
    out[LABEL_OFF + b * MAXDET + tid] = lb;
    out[KEEP_OFF + b * MAXDET + tid] = kp;
  }
}

extern "C" void kernel_launch(void* const* d_in, const int* in_sizes, int n_in,
                              void* d_out, int out_size, void* d_ws, size_t ws_size,
                              hipStream_t stream) {
  const float* logits = (const float*)d_in[0];
  const float* rel = (const float*)d_in[1];
  const float* props = (const float*)d_in[2];
  const int* ph = (const int*)d_in[3];
  const int* pw = (const int*)d_in[4];
  float* out = (float*)d_out;

  // ws layout (448 KB):
  char* ws = (char*)d_ws;
  float4* cand_box = (float4*)ws;                                              // 256 KB
  unsigned long long* keys = (unsigned long long*)(ws + (size_t)BB * MM * 16); // 128 KB
  unsigned* hist_g = (unsigned*)(ws + (size_t)BB * MM * 16 + (size_t)BB * MM * 8); // 64 KB (16 blocks x 1024 bins)

  decode_kernel<<<16, 512, 0, stream>>>(logits, rel, props, ph, pw, cand_box,
                                        keys, hist_g, out);
  nms_kernel<<<BB, 512, 0, stream>>>(cand_box, keys, hist_g, out);
}

// Round 9
// 93.277 us; speedup vs baseline: 1.1958x; 1.0154x over previous
//
#include <hip/hip_runtime.h>
#include <stdint.h>

#define BB 4
#define NN 2048
#define CC 3
#define MM (NN * (CC - 1)) /* 4096 */
#define MAXDET 100
#define SCORE_THR 0.05f
#define NMS_THR 0.5f
#define MIN_SIZE 0.01f
#define TTARGET 256 /* selection prefix size (scan depth ~115 on this data) */
#define SSKCAP 1024 /* mid-path sort buffer capacity */
#define TILE 128    /* NMS tile size */

// out layout: boxes[4,100,4] ++ scores[4,100] ++ labels[4,100] ++ keep[4,100]
#define SCORE_OFF (BB * MAXDET * 4)         /* 1600 */
#define LABEL_OFF (SCORE_OFF + BB * MAXDET) /* 2000 */
#define KEEP_OFF (LABEL_OFF + BB * MAXDET)  /* 2400 */

// Wave-local LDS sync (r4-validated).
__device__ __forceinline__ void wave_lds_sync() {
  __builtin_amdgcn_wave_barrier();
  __builtin_amdgcn_s_waitcnt(0xC07F); // vmcnt(63) expcnt(7) lgkmcnt(0)
  __builtin_amdgcn_wave_barrier();
}

// Exact reference IoU>thr test (validated absmax=0 across rounds 1-8).
__device__ __forceinline__ bool iou_gt(const float4 A, const float aA,
                                       const float4 B, const float aB) {
#pragma clang fp contract(off)
  float ltx = fmaxf(A.x, B.x), lty = fmaxf(A.y, B.y);
  float rbx = fminf(A.z, B.z), rby = fminf(A.w, B.w);
  float iw = fmaxf(rbx - ltx, 0.0f), ih = fmaxf(rby - lty, 0.0f);
  float inter = iw * ih;
  float denom = ((aA + aB) - inter) + 1e-7f;
  return inter / denom > NMS_THR;
}

// ---------------------------------------------------------------------------
// Block-wide hybrid bitonic sort (mid/fallback paths; r4/r5-validated).
// ---------------------------------------------------------------------------
__device__ void bitonic_sort_desc(unsigned long long* a, int P, int tid) {
  int prev_big = 1;
  for (int size = 2; size <= P; size <<= 1) {
    for (int stride = size >> 1; stride > 0; stride >>= 1) {
      int big = (stride >= 128);
      if (big | prev_big) __syncthreads(); else wave_lds_sync();
      for (int i = tid; i < (P >> 1); i += 512) {
        int lo = 2 * i - (i & (stride - 1));
        int hi = lo + stride;
        bool asc = ((lo & size) != 0);
        unsigned long long x = a[lo], y = a[hi];
        if ((x > y) == asc) { a[lo] = y; a[hi] = x; }
      }
      prev_big = big;
    }
  }
  __syncthreads();
}

// ---------------------------------------------------------------------------
// Register bitonic sort of exactly 512 elements, 1/thread (r7-validated).
// ---------------------------------------------------------------------------
__device__ void bitonic_sort_desc_reg512(unsigned long long* a,
                                         unsigned long long* xbuf0,
                                         unsigned long long* xbuf1,
                                         int T, int tid) {
  unsigned long long v = (tid < T) ? a[tid] : 0ull;
  int xb = 0;
  for (int size = 2; size <= 512; size <<= 1) {
    for (int stride = size >> 1; stride > 0; stride >>= 1) {
      unsigned long long o;
      if (stride < 64) {
        o = __shfl_xor(v, stride);
      } else {
        unsigned long long* buf = xb ? xbuf1 : xbuf0;
        __syncthreads();
        buf[tid] = v;
        __syncthreads();
        o = buf[tid ^ stride];
        xb ^= 1;
      }
      bool is_lo = (tid & stride) == 0;
      bool asc = (tid & size) != 0;
      bool take_min = (asc == is_lo);
      bool o_less = (o < v);
      unsigned long long mn = o_less ? o : v;
      unsigned long long mx = o_less ? v : o;
      v = take_min ? mn : mx;
    }
  }
  __syncthreads();
  a[tid] = v;
  __syncthreads();
}

// ---------------------------------------------------------------------------
// Mask-based tiled greedy NMS (exact; r5-r8 validated logic). All candidate
// boxes live in LDS (sboxes[m]) — gathers, appends and output need no global.
// Whole block must call (contains barriers). Returns final kept count.
// ---------------------------------------------------------------------------
__device__ int tiled_nms(const unsigned long long* keys_s, int count,
                         const float4* sboxes, float off_base,
                         float4* tob, float* tarea,
                         ulonglong2* smask, int* sflag, int* knew,
                         float4* kept_ob, float* kept_area,
                         unsigned long long* kept_key, int* s_nnew, int tid) {
#pragma clang fp contract(off)
  int wv = tid >> 6, lane = tid & 63;
  int cnt = 0;
  for (int base = 0; base < count && cnt < MAXDET; base += TILE) {
    int tsz = (count - base < TILE) ? (count - base) : TILE;
    // gather tile: offset box + area (exact offset arithmetic)
    if (tid < tsz) {
      unsigned long long key = keys_s[base + tid];
      int m = (int)(0xFFFFFFFFu - (unsigned)key);
      float4 bx = sboxes[m];
      int lbl = (m & 1) + 1;
      float off = (float)lbl * off_base;
      float4 ob = make_float4(bx.x + off, bx.y + off, bx.z + off, bx.w + off);
      tob[tid] = ob;
      tarea[tid] = (ob.z - ob.x) * (ob.w - ob.y);
    }
    __syncthreads();

    // per-lane register copies (invariant across rows of this tile)
    float4 bi0 = tob[lane];
    float ai0 = tarea[lane];
    float4 bi1 = tob[lane + 64];
    float ai1 = tarea[lane + 64];
    float4 kb0 = kept_ob[(lane < cnt) ? lane : 0];
    float ka0 = kept_area[(lane < cnt) ? lane : 0];
    float4 kb1 = kept_ob[(lane + 64 < cnt) ? lane + 64 : 0];
    float ka1 = kept_area[(lane + 64 < cnt) ? lane + 64 : 0];

    // matrix phase: wave wv handles rows j = wv, wv+8, ...
    for (int j = wv; j < tsz; j += 8) {
      float4 aj = tob[j];
      float aaj = tarea[j];
      unsigned long long w0 = 0ull, w1 = 0ull;
      if (j < 63) {
        bool p = (lane > j) && (lane < tsz) && iou_gt(aj, aaj, bi0, ai0);
        w0 = __ballot(p);
      }
      if (j < 127) {
        int i = lane + 64;
        bool p = (i > j) && (i < tsz) && iou_gt(aj, aaj, bi1, ai1);
        w1 = __ballot(p);
      }
      bool s = false;
      if (cnt > 0) {
        if (lane < cnt && iou_gt(kb0, ka0, aj, aaj)) s = true;
        if (cnt > 64 && lane + 64 < cnt && iou_gt(kb1, ka1, aj, aaj)) s = true;
      }
      int anyk = __any(s);
      if (lane == 0) {
        smask[j].x = w0;
        smask[j].y = w1;
        sflag[j] = anyk;
      }
    }
    __syncthreads();

    // serial bit reduction on wave 0 — uniform across lanes, rows broadcast
    // from LDS via a 4-deep prefetch ring (r8-validated).
    if (tid < 64) {
      bool f0 = (lane < tsz) && (sflag[lane] != 0);
      unsigned long long remv0 = __ballot(f0);
      bool f1 = (lane + 64 < tsz) && (sflag[lane + 64] != 0);
      unsigned long long remv1 = __ballot(f1);
      ulonglong2 pre[4];
#pragma unroll
      for (int k = 0; k < 4; ++k) pre[k] = smask[(k < tsz) ? k : 0];
      int c = cnt, nk = 0;
      for (int j = 0; j < tsz; ++j) {
        ulonglong2 row = pre[j & 3];
        int nxt = j + 4;
        pre[j & 3] = smask[(nxt < tsz) ? nxt : 0];
        bool rem = (j < 64) ? (((remv0 >> j) & 1ull) != 0ull)
                            : (((remv1 >> (j - 64)) & 1ull) != 0ull);
        if (!rem) {
          if (lane == 0) knew[nk] = j;
          nk++;
          c++;
          remv0 |= row.x;
          remv1 |= row.y;
          if (c >= MAXDET) break;
        }
      }
      if (lane == 0) *s_nnew = nk;
    }
    __syncthreads();

    // append new keeps (parallel)
    int nnew = *s_nnew;
    if (tid < nnew) {
      int j = knew[tid];
      kept_ob[cnt + tid] = tob[j];
      kept_area[cnt + tid] = tarea[j];
      kept_key[cnt + tid] = keys_s[base + j];
    }
    cnt += nnew;
    __syncthreads();
  }
  return cnt;
}

// ---------------------------------------------------------------------------
// fused_kernel: one block per image, everything in one dispatch.
//  decode 4 proposals/thread -> boxes to LDS, keys to registers, LDS hist ->
//  block max reduce -> wave-0 suffix scan (threshold) -> ballot-compaction ->
//  register shfl sort (T<=512) / hybrid LDS sort (T<=1024) -> tiled NMS with
//  LDS-only box access. Fallback: full 4096 sort from register keys (exact on
//  any data). FP arithmetic bitwise-identical to rounds 1-8 (absmax 0.0).
// ---------------------------------------------------------------------------
__global__ __launch_bounds__(512) void fused_kernel(const float* __restrict__ logits,
                                                    const float* __restrict__ rel,
                                                    const float* __restrict__ props,
                                                    const int* __restrict__ ph,
                                                    const int* __restrict__ pw,
                                                    float* __restrict__ out) {
#pragma clang fp contract(off)
  __shared__ __align__(16) float4 sboxes[MM];              // 64 KB all cand boxes
  __shared__ __align__(16) unsigned long long sk[MM];      // 32 KB fallback + xbuf
  __shared__ __align__(16) unsigned long long ssk[SSKCAP]; // 8 KB selected keys
  __shared__ unsigned hist[1024];                          // 4 KB
  __shared__ float red[512];                               // 2 KB
  __shared__ __align__(16) float4 tob[TILE];
  __shared__ float tarea[TILE];
  __shared__ __align__(16) ulonglong2 smask[TILE];
  __shared__ int sflag[TILE];
  __shared__ int knew[TILE];
  __shared__ float4 kept_ob[MAXDET];
  __shared__ float kept_area[MAXDET];
  __shared__ unsigned long long kept_key[MAXDET];
  __shared__ int s_scnt, s_thr, s_vtot, s_cnt, s_fb, s_nnew;

  int b = blockIdx.x;
  int tid = threadIdx.x;
  int lane = tid & 63;

  hist[tid] = 0u;
  hist[tid + 512] = 0u;
  if (tid == 0) { s_scnt = 0; s_fb = 0; s_cnt = 0; }
  __syncthreads();

  // ---- decode phase: 4 proposals/thread (8 candidates) ----
  float Hf = (float)ph[0];
  float Wf = (float)pw[0];
  const float SCALE_CLAMP = 4.135166556742356f; // log(1000/16) as f32
  ulonglong2 kr[4];
  float lmax = 0.0f;
#pragma unroll
  for (int k = 0; k < 4; ++k) {
    int n = tid + k * 512;
    int t = b * NN + n;
    const float* lg = logits + (size_t)t * CC;
    float l0 = lg[0], l1 = lg[1], l2 = lg[2];
    float mx = fmaxf(l0, fmaxf(l1, l2));
    float e0 = expf(l0 - mx), e1 = expf(l1 - mx), e2 = expf(l2 - mx);
    float ssum = (e0 + e1) + e2;

    float4 pr = ((const float4*)props)[t];
    float w = pr.z - pr.x, h = pr.w - pr.y;
    float cx = pr.x + 0.5f * w, cy = pr.y + 0.5f * h;
    const float4* rl = (const float4*)(rel + (size_t)t * 12);

    unsigned long long kk[2];
    for (int c = 1; c < CC; ++c) {
      float4 rv = rl[c];
      float score = (c == 1 ? e1 : e2) / ssum;
      float dx = rv.x / 10.0f;
      float dy = rv.y / 10.0f;
      float dw = fminf(rv.z / 5.0f, SCALE_CLAMP);
      float dh = fminf(rv.w / 5.0f, SCALE_CLAMP);
      float pcx = dx * w + cx;
      float pcy = dy * h + cy;
      float bw = expf(dw) * w;
      float bh = expf(dh) * h;
      float x1 = pcx - 0.5f * bw, y1 = pcy - 0.5f * bh;
      float x2 = pcx + 0.5f * bw, y2 = pcy + 0.5f * bh;
      x1 = fminf(fmaxf(x1, 0.0f), Wf);
      y1 = fminf(fmaxf(y1, 0.0f), Hf);
      x2 = fminf(fmaxf(x2, 0.0f), Wf);
      y2 = fminf(fmaxf(y2, 0.0f), Hf);

      // jnp.max(boxes) is over ALL candidate boxes (incl. invalid)
      lmax = fmaxf(lmax, fmaxf(fmaxf(x1, y1), fmaxf(x2, y2)));

      bool valid = (score > SCORE_THR) && (x2 - x1 >= MIN_SIZE) && (y2 - y1 >= MIN_SIZE);
      int m = n * (CC - 1) + (c - 1);
      sboxes[m] = make_float4(x1, y1, x2, y2);
      unsigned long long key = 0ull;
      if (valid) {
        unsigned sb = __float_as_uint(score);
        key = (((unsigned long long)sb) << 32) |
              (unsigned long long)(0xFFFFFFFFu - (unsigned)m);
        // bin = score bits[25:16]; monotone in score over (0.05,1] (validated)
        atomicAdd(&hist[(sb >> 16) & 1023], 1u);
      }
      kk[c - 1] = key;
    }
    kr[k].x = kk[0];
    kr[k].y = kk[1];
  }

  // block max reduce -> offset base (barriers also fence sboxes/hist writes)
  red[tid] = lmax;
  __syncthreads();
  for (int s2 = 256; s2 > 0; s2 >>= 1) {
    if (tid < s2) red[tid] = fmaxf(red[tid], red[tid + s2]);
    __syncthreads();
  }
  float off_base = red[0] + 1.0f;

  // wave 0: suffix scan of LDS hist; threshold = largest bin suffix>=TTARGET
  if (tid < 64) {
    unsigned own[16];
#pragma unroll
    for (int i = 0; i < 16; ++i) own[i] = hist[tid * 16 + i];
    unsigned psum = 0;
#pragma unroll
    for (int i = 0; i < 16; ++i) psum += own[i];
    unsigned s = psum;
    for (int d = 1; d < 64; d <<= 1) {
      unsigned o = __shfl_down(s, d);
      if (tid + d < 64) s += o;
    }
    unsigned after = s - psum;
    int best = -1;
    unsigned run = after;
#pragma unroll
    for (int i = 15; i >= 0; --i) {
      run += own[i];
      if (best < 0 && run >= TTARGET) best = tid * 16 + i;
    }
    int gb = best;
    for (int d = 1; d < 64; d <<= 1) {
      int o = __shfl_down(gb, d);
      if (tid + d < 64) gb = (o > gb) ? o : gb;
    }
    if (tid == 0) {
      s_thr = (gb < 0) ? 0 : gb;
      s_vtot = (int)s;
    }
  }
  __syncthreads();
  int thr = s_thr;
  int Vtot = s_vtot;

  // ballot-compaction of selected keys into ssk (boxes already in LDS)
#pragma unroll
  for (int j = 0; j < 4; ++j) {
#pragma unroll
    for (int half = 0; half < 2; ++half) {
      unsigned long long key = half ? kr[j].y : kr[j].x;
      unsigned hik = (unsigned)(key >> 32);
      bool pred = (hik != 0u) && ((int)((hik >> 16) & 1023) >= thr);
      unsigned long long mask = __ballot(pred);
      int ofs = __popcll(mask & ((1ull << lane) - 1ull));
      int basea = 0;
      if (lane == 0 && mask) basea = atomicAdd(&s_scnt, (int)__popcll(mask));
      basea = __shfl(basea, 0);
      if (pred) {
        int pos = basea + ofs;
        if (pos < SSKCAP) ssk[pos] = key;
      }
    }
  }
  __syncthreads();
  int T = s_scnt;

  if (T <= SSKCAP) {
    if (T <= 512) {
      bitonic_sort_desc_reg512(ssk, sk, sk + 512, T, tid);
    } else {
      int P = 1;
      while (P < T) P <<= 1;
      for (int i = T + tid; i < P; i += 512) ssk[i] = 0ull;
      __syncthreads();
      bitonic_sort_desc(ssk, P, tid);
    }
    int cnt = tiled_nms(ssk, T, sboxes, off_base, tob, tarea, smask, sflag,
                        knew, kept_ob, kept_area, kept_key, &s_nnew, tid);
    if (tid == 0) {
      s_cnt = cnt;
      s_fb = (cnt < MAXDET && T < Vtot) ? 1 : 0; // prefix insufficient
    }
  } else {
    if (tid == 0) s_fb = 1; // selection overflow (degenerate ties)
  }
  __syncthreads();

  if (s_fb) {
    // exact slow path: rebuild all keys from registers, full sort, rerun NMS
    ulonglong2* skp = (ulonglong2*)sk;
#pragma unroll
    for (int j = 0; j < 4; ++j) skp[j * 512 + tid] = kr[j];
    __syncthreads();
    bitonic_sort_desc(sk, MM, tid);
    int cnt = tiled_nms(sk, Vtot, sboxes, off_base, tob, tarea, smask, sflag,
                        knew, kept_ob, kept_area, kept_key, &s_nnew, tid);
    if (tid == 0) s_cnt = cnt;
    __syncthreads();
  }

  // output: rows [0,cnt) from kept arrays (boxes via LDS), rest zeros.
  int cnt = s_cnt;
  if (tid < MAXDET) {
    float4 bx = make_float4(0.0f, 0.0f, 0.0f, 0.0f);
    float sc = 0.0f, lb = 0.0f, kp = 0.0f;
    if (tid < cnt) {
      unsigned long long key = kept_key[tid];
      int m = (int)(0xFFFFFFFFu - (unsigned)key);
      bx = sboxes[m];
      sc = __uint_as_float((unsigned)(key >> 32));
      lb = (float)((m & 1) + 1);
      kp = 1.0f;
    }
    float* obp = out + (size_t)b * MAXDET * 4 + (size_t)tid * 4;
    obp[0] = bx.x; obp[1] = bx.y; obp[2] = bx.z; obp[3] = bx.w;
    out[SCORE_OFF + b * MAXDET + tid] = sc;
    out[LABEL_OFF + b * MAXDET + tid] = lb;
    out[KEEP_OFF + b * MAXDET + tid] = kp;
  }
}

extern "C" void kernel_launch(void* const* d_in, const int* in_sizes, int n_in,
                              void* d_out, int out_size, void* d_ws, size_t ws_size,
                              hipStream_t stream) {
  const float* logits = (const float*)d_in[0];
  const float* rel = (const float*)d_in[1];
  const float* props = (const float*)d_in[2];
  const int* ph = (const int*)d_in[3];
  const int* pw = (const int*)d_in[4];
  float* out = (float*)d_out;
  (void)d_ws; (void)ws_size; // everything lives in LDS/registers now

  fused_kernel<<<BB, 512, 0, stream>>>(logits, rel, props, ph, pw, out);
}